// Round 1
// baseline (1838.117 us; speedup 1.0000x reference)
//
#include <hip/hip_runtime.h>
#include <math.h>

// ---------------------------------------------------------------------------
// Model dims (fixed by the reference)
//   BS=1024 T=10 N=10240 H=256 C=128(H/2) E=50 SEQ=50 V=50000 NREG=1
// ---------------------------------------------------------------------------

__global__ __launch_bounds__(256) void k_zero(float* __restrict__ p, int n) {
  int i = blockIdx.x * 256 + threadIdx.x;
  if (i < n) p[i] = 0.f;
}

// conv3 weights [128][50][3] -> w3p [e=50][c=128][k=4] (k=3 padded)
__global__ __launch_bounds__(256) void k_repack3(const float* __restrict__ w3,
                                                 float* __restrict__ w3p) {
  int i = blockIdx.x * 256 + threadIdx.x;   // 25600
  if (i >= 25600) return;
  int e = i >> 9, r = i & 511, c = r >> 2, k = r & 3;
  w3p[i] = (k < 3) ? w3[c * 150 + e * 3 + k] : 0.f;
}

// conv4 weights [128][128][4] -> w4p [ci=128][c=128][k=4]
__global__ __launch_bounds__(256) void k_repack4(const float* __restrict__ w4,
                                                 float* __restrict__ w4p) {
  int i = blockIdx.x * 256 + threadIdx.x;   // 65536
  int ci = i >> 9, r = i & 511, c = r >> 2, k = r & 3;
  w4p[i] = w4[c * 512 + ci * 4 + k];
}

// gru_whh [768][256] -> whhT [c=256][j=768]
__global__ __launch_bounds__(256) void k_whht(const float* __restrict__ whh,
                                              float* __restrict__ whhT) {
  int j = blockIdx.x, t = threadIdx.x;
  whhT[t * 768 + j] = whh[j * 256 + t];
}

// Wcomb[g][c] = sum_j gru_wih[g][j]*mh_w[j][c];  b1[g] = gru_bih[g] + sum_j wih[g][j]*mh_b[j]
__global__ __launch_bounds__(256) void k_pcomb(const float* __restrict__ wih,
                                               const float* __restrict__ mh_w,
                                               const float* __restrict__ mh_b,
                                               const float* __restrict__ bih,
                                               float* __restrict__ Wcomb,
                                               float* __restrict__ b1) {
  int g = blockIdx.x, t = threadIdx.x;
  float acc = 0.f;
  for (int j = 0; j < 256; ++j) acc += wih[g * 256 + j] * mh_w[j * 256 + t];
  Wcomb[g * 256 + t] = acc;
  float accb = wih[g * 256 + t] * mh_b[t];
  accb += __shfl_down(accb, 32); accb += __shfl_down(accb, 16);
  accb += __shfl_down(accb, 8);  accb += __shfl_down(accb, 4);
  accb += __shfl_down(accb, 2);  accb += __shfl_down(accb, 1);
  __shared__ float red[4];
  if ((t & 63) == 0) red[t >> 6] = accb;
  __syncthreads();
  if (t == 0) b1[g] = bih[g] + red[0] + red[1] + red[2] + red[3];
}

// Fold lags/weather/event/text projections through merge_w.
// blocks 0..127: MtxT[c][t] = sum_j merge_w[t][768+j]*text_w[j][c]
// block 128: A_l, MwT, MeT, bias_deg
__global__ __launch_bounds__(256) void k_pmerge(const float* __restrict__ merge_w,
                                                const float* __restrict__ text_w,
                                                const float* __restrict__ lags_w,
                                                const float* __restrict__ weather_w,
                                                const float* __restrict__ event_w,
                                                const float* __restrict__ lags_b,
                                                const float* __restrict__ weather_b,
                                                const float* __restrict__ event_b,
                                                const float* __restrict__ text_b,
                                                float* __restrict__ MtxT,
                                                float* __restrict__ A_l,
                                                float* __restrict__ MwT,
                                                float* __restrict__ MeT,
                                                float* __restrict__ bias_deg) {
  int blk = blockIdx.x, t = threadIdx.x;
  if (blk < 128) {
    int c = blk;
    float acc = 0.f;
    for (int j = 0; j < 256; ++j)
      acc += merge_w[t * 1024 + 768 + j] * text_w[j * 128 + c];
    MtxT[c * 256 + t] = acc;
  } else {
    float a = 0.f, w0 = 0.f, w1 = 0.f, e0 = 0.f, e1 = 0.f, e2 = 0.f, e3 = 0.f, bd = 0.f;
    for (int j = 0; j < 256; ++j) {
      float m0 = merge_w[t * 1024 + j];
      float m1 = merge_w[t * 1024 + 256 + j];
      float m2 = merge_w[t * 1024 + 512 + j];
      float m3 = merge_w[t * 1024 + 768 + j];
      a  += m0 * lags_w[j];
      w0 += m1 * weather_w[j * 2 + 0];
      w1 += m1 * weather_w[j * 2 + 1];
      e0 += m2 * event_w[j * 4 + 0];
      e1 += m2 * event_w[j * 4 + 1];
      e2 += m2 * event_w[j * 4 + 2];
      e3 += m2 * event_w[j * 4 + 3];
      bd += m0 * lags_b[j] + m1 * weather_b[j] + m2 * event_b[j] + m3 * text_b[j];
    }
    A_l[t] = a;
    MwT[t] = w0; MwT[256 + t] = w1;
    MeT[t] = e0; MeT[256 + t] = e1; MeT[512 + t] = e2; MeT[768 + t] = e3;
    bias_deg[t] = bd;
  }
}

__device__ inline void ld16(const float* p, float* x) {
  const float4* q = (const float4*)p;
  float4 a = q[0], b = q[1], c = q[2], d = q[3];
  x[0] = a.x; x[1] = a.y; x[2]  = a.z; x[3]  = a.w;
  x[4] = b.x; x[5] = b.y; x[6]  = b.z; x[7]  = b.w;
  x[8] = c.x; x[9] = c.y; x[10] = c.z; x[11] = c.w;
  x[12] = d.x; x[13] = d.y; x[14] = d.z; x[15] = d.w;
}

// Fused per-node text CNN: gather emb -> conv3(relu) -> conv4(relu) -> max_p -> mx[n][128]
// One block per node; 4 p-quarters x 64 channel-lanes; each thread owns channels c0,c0+64.
__global__ __launch_bounds__(256) void k_textcnn(const int* __restrict__ text,
                                                 const float* __restrict__ emb,
                                                 const float* __restrict__ w3p,
                                                 const float* __restrict__ b3,
                                                 const float* __restrict__ w4p,
                                                 const float* __restrict__ b4,
                                                 float* __restrict__ mx_g) {
  __shared__ __align__(16) float x_lds[2600];    // [e=50][s: stride 52]
  __shared__ __align__(16) float c3_lds[6656];   // [ci=128][p: stride 52]
  __shared__ int idx_lds[50];
  const int n = blockIdx.x;
  const int tid = threadIdx.x;
  if (tid < 50) idx_lds[tid] = text[n * 50 + tid];
  __syncthreads();
  for (int f = tid; f < 2500; f += 256) {
    int s = f / 50;
    int e = f - s * 50;
    x_lds[e * 52 + s] = emb[idx_lds[s] * 50 + e];
  }
  __syncthreads();
  const int c0 = tid & 63;
  const int ph = tid >> 6;
  const int p0 = ph * 12;

  // conv3: out[c][p], p in [p0, p0+12)
  float acc0[12], acc1[12];
#pragma unroll
  for (int i = 0; i < 12; ++i) { acc0[i] = 0.f; acc1[i] = 0.f; }
  for (int e = 0; e < 50; ++e) {
    float xw[16];
    ld16(&x_lds[e * 52 + p0], xw);               // broadcast reads, 16B aligned
    float4 w0 = *(const float4*)&w3p[e * 512 + c0 * 4];
    float4 w1 = *(const float4*)&w3p[e * 512 + c0 * 4 + 256];
#pragma unroll
    for (int pl = 0; pl < 12; ++pl) {
      acc0[pl] += xw[pl] * w0.x + xw[pl + 1] * w0.y + xw[pl + 2] * w0.z;
      acc1[pl] += xw[pl] * w1.x + xw[pl + 1] * w1.y + xw[pl + 2] * w1.z;
    }
  }
  {
    float ba = b3[c0], bb = b3[c0 + 64];
#pragma unroll
    for (int pl = 0; pl < 12; ++pl) {
      c3_lds[c0 * 52 + p0 + pl]        = fmaxf(acc0[pl] + ba, 0.f);
      c3_lds[(c0 + 64) * 52 + p0 + pl] = fmaxf(acc1[pl] + bb, 0.f);
    }
  }
  __syncthreads();

  // conv4: 45 outputs = 12+12+12+9 per quarter
  float a40[12], a41[12];
#pragma unroll
  for (int i = 0; i < 12; ++i) { a40[i] = 0.f; a41[i] = 0.f; }
  for (int ci = 0; ci < 128; ++ci) {
    float xw[16];
    ld16(&c3_lds[ci * 52 + p0], xw);
    float4 w0 = *(const float4*)&w4p[ci * 512 + c0 * 4];
    float4 w1 = *(const float4*)&w4p[ci * 512 + c0 * 4 + 256];
#pragma unroll
    for (int pl = 0; pl < 12; ++pl) {
      a40[pl] += xw[pl] * w0.x + xw[pl + 1] * w0.y + xw[pl + 2] * w0.z + xw[pl + 3] * w0.w;
      a41[pl] += xw[pl] * w1.x + xw[pl + 1] * w1.y + xw[pl + 2] * w1.z + xw[pl + 3] * w1.w;
    }
  }
  const int np = (ph == 3) ? 9 : 12;
  float v0 = -1e30f, v1 = -1e30f;
  for (int pl = 0; pl < np; ++pl) { v0 = fmaxf(v0, a40[pl]); v1 = fmaxf(v1, a41[pl]); }
  v0 = fmaxf(v0 + b4[c0], 0.f);
  v1 = fmaxf(v1 + b4[c0 + 64], 0.f);
  float* part = x_lds;                            // x region is dead after conv3 (sync'd)
  part[ph * 128 + c0] = v0;
  part[ph * 128 + c0 + 64] = v1;
  __syncthreads();
  if (tid < 128) {
    float mv = fmaxf(fmaxf(part[tid], part[128 + tid]),
                     fmaxf(part[256 + tid], part[384 + tid]));
    mx_g[n * 128 + tid] = mv;
  }
}

__device__ inline void preds_of(int i, int& p1, int& p2, int& d) {
  int tt = i % 10;
  int base = i - tt;
  if (tt == 0)      { p1 = base + 9;      p2 = -1;             d = 1; }
  else if (tt == 1) { p1 = base;          p2 = -1;             d = 1; }
  else              { p1 = base + tt - 2; p2 = base + tt - 1;  d = 2; }
}

// graph agg + folded merge -> m[N][256] (relu'd), + BN channel sums via atomics
__global__ __launch_bounds__(256) void k_merge(const float* __restrict__ mx_g,
                                               const float* __restrict__ lags,
                                               const float* __restrict__ weather,
                                               const float* __restrict__ event,
                                               const float* __restrict__ MtxT,
                                               const float* __restrict__ A_l,
                                               const float* __restrict__ MwT,
                                               const float* __restrict__ MeT,
                                               const float* __restrict__ bias_deg,
                                               const float* __restrict__ merge_b,
                                               float* __restrict__ m_out,
                                               float* __restrict__ bnsum,
                                               float* __restrict__ bnsumsq) {
  __shared__ __align__(16) float mxs[16 * 128];
  __shared__ float scal[16 * 8];
  const int tid = threadIdx.x;
  const int row0 = blockIdx.x * 16;
  for (int idx = tid; idx < 2048; idx += 256) {
    int r = idx >> 7, c = idx & 127;
    int p1, p2, d;
    preds_of(row0 + r, p1, p2, d);
    float v = mx_g[p1 * 128 + c];
    if (p2 >= 0) v += mx_g[p2 * 128 + c];
    mxs[r * 128 + c] = v;
  }
  if (tid < 16) {
    int p1, p2, d;
    preds_of(row0 + tid, p1, p2, d);
    float sl = lags[p1];
    float sw0 = weather[p1 * 2], sw1 = weather[p1 * 2 + 1];
    float se0 = event[p1 * 4], se1 = event[p1 * 4 + 1];
    float se2 = event[p1 * 4 + 2], se3 = event[p1 * 4 + 3];
    if (p2 >= 0) {
      sl += lags[p2];
      sw0 += weather[p2 * 2]; sw1 += weather[p2 * 2 + 1];
      se0 += event[p2 * 4];     se1 += event[p2 * 4 + 1];
      se2 += event[p2 * 4 + 2]; se3 += event[p2 * 4 + 3];
    }
    scal[tid * 8 + 0] = sl;
    scal[tid * 8 + 1] = sw0; scal[tid * 8 + 2] = sw1;
    scal[tid * 8 + 3] = se0; scal[tid * 8 + 4] = se1;
    scal[tid * 8 + 5] = se2; scal[tid * 8 + 6] = se3;
    scal[tid * 8 + 7] = (float)d;
  }
  __syncthreads();
  const int t = tid;
  float acc[16];
#pragma unroll
  for (int r = 0; r < 16; ++r) acc[r] = 0.f;
  for (int c4 = 0; c4 < 32; ++c4) {
    const int c = c4 * 4;
    float w0 = MtxT[c * 256 + t];
    float w1 = MtxT[(c + 1) * 256 + t];
    float w2 = MtxT[(c + 2) * 256 + t];
    float w3 = MtxT[(c + 3) * 256 + t];
#pragma unroll
    for (int r = 0; r < 16; ++r) {
      float4 mv = *(const float4*)&mxs[r * 128 + c];
      acc[r] += mv.x * w0 + mv.y * w1 + mv.z * w2 + mv.w * w3;
    }
  }
  float al = A_l[t], mw0 = MwT[t], mw1 = MwT[256 + t];
  float me0 = MeT[t], me1 = MeT[256 + t], me2 = MeT[512 + t], me3 = MeT[768 + t];
  float bd = bias_deg[t], mb = merge_b[t];
  float s1 = 0.f, s2 = 0.f;
#pragma unroll
  for (int r = 0; r < 16; ++r) {
    float mp = acc[r] + scal[r * 8] * al + scal[r * 8 + 1] * mw0 + scal[r * 8 + 2] * mw1
             + scal[r * 8 + 3] * me0 + scal[r * 8 + 4] * me1 + scal[r * 8 + 5] * me2
             + scal[r * 8 + 6] * me3 + scal[r * 8 + 7] * bd + mb;
    float mv = fmaxf(mp, 0.f);
    m_out[(row0 + r) * 256 + t] = mv;
    s1 += mv;
    s2 += mv * mv;
  }
  atomicAdd(&bnsum[t], s1);
  atomicAdd(&bnsumsq[t], s2);
}

// BN finalize -> per-channel scale s and shift term
__global__ __launch_bounds__(256) void k_bna(const float* __restrict__ bnsum,
                                             const float* __restrict__ bnsumsq,
                                             const float* __restrict__ gamma,
                                             const float* __restrict__ beta,
                                             float* __restrict__ svec,
                                             float* __restrict__ tvec) {
  int c = threadIdx.x;
  float mu = bnsum[c] * (1.f / 10240.f);
  float var = bnsumsq[c] * (1.f / 10240.f) - mu * mu;
  float s = gamma[c] * rsqrtf(var + 1e-5f);
  svec[c] = s;
  tvec[c] = beta[c] - mu * s;
}

// WbigT[c][g] = Wcomb[g][c]*s[c]
__global__ __launch_bounds__(256) void k_bnb(const float* __restrict__ Wcomb,
                                             const float* __restrict__ svec,
                                             float* __restrict__ WbigT) {
  int i = blockIdx.x * 256 + threadIdx.x;   // 196608
  int c = i / 768, g = i - c * 768;
  WbigT[i] = Wcomb[g * 256 + c] * svec[c];
}

// bias_big[g] = b1[g] + sum_c tvec[c]*Wcomb[g][c]
__global__ __launch_bounds__(256) void k_bnc(const float* __restrict__ Wcomb,
                                             const float* __restrict__ tvec,
                                             const float* __restrict__ b1,
                                             float* __restrict__ bias_big) {
  int g = blockIdx.x, c = threadIdx.x;
  float part = tvec[c] * Wcomb[g * 256 + c];
  part += __shfl_down(part, 32); part += __shfl_down(part, 16);
  part += __shfl_down(part, 8);  part += __shfl_down(part, 4);
  part += __shfl_down(part, 2);  part += __shfl_down(part, 1);
  __shared__ float red[4];
  if ((c & 63) == 0) red[c >> 6] = part;
  __syncthreads();
  if (c == 0) bias_big[g] = b1[g] + red[0] + red[1] + red[2] + red[3];
}

// gi[N][768] = m @ WbigT + bias_big   (BN+mh+Wih all folded in)
__global__ __launch_bounds__(256) void k_gi(const float* __restrict__ m,
                                            const float* __restrict__ WbigT,
                                            const float* __restrict__ bias_big,
                                            float* __restrict__ gi) {
  __shared__ __align__(16) float ml[16 * 256];
  const int t = threadIdx.x;
  const int row0 = blockIdx.x * 16;
  for (int idx = t; idx < 4096; idx += 256) ml[idx] = m[row0 * 256 + idx];
  __syncthreads();
  float a0[16], a1[16], a2[16];
#pragma unroll
  for (int r = 0; r < 16; ++r) { a0[r] = 0.f; a1[r] = 0.f; a2[r] = 0.f; }
  for (int c4 = 0; c4 < 64; ++c4) {
    const int c = c4 * 4;
    float w00 = WbigT[c * 768 + t];
    float w01 = WbigT[(c + 1) * 768 + t];
    float w02 = WbigT[(c + 2) * 768 + t];
    float w03 = WbigT[(c + 3) * 768 + t];
    float w10 = WbigT[c * 768 + 256 + t];
    float w11 = WbigT[(c + 1) * 768 + 256 + t];
    float w12 = WbigT[(c + 2) * 768 + 256 + t];
    float w13 = WbigT[(c + 3) * 768 + 256 + t];
    float w20 = WbigT[c * 768 + 512 + t];
    float w21 = WbigT[(c + 1) * 768 + 512 + t];
    float w22 = WbigT[(c + 2) * 768 + 512 + t];
    float w23 = WbigT[(c + 3) * 768 + 512 + t];
#pragma unroll
    for (int r = 0; r < 16; ++r) {
      float4 mv = *(const float4*)&ml[r * 256 + c];
      a0[r] += mv.x * w00 + mv.y * w01 + mv.z * w02 + mv.w * w03;
      a1[r] += mv.x * w10 + mv.y * w11 + mv.z * w12 + mv.w * w13;
      a2[r] += mv.x * w20 + mv.y * w21 + mv.z * w22 + mv.w * w23;
    }
  }
  float b0 = bias_big[t], b1v = bias_big[256 + t], b2v = bias_big[512 + t];
#pragma unroll
  for (int r = 0; r < 16; ++r) {
    int node = row0 + r;
    gi[node * 768 + t] = a0[r] + b0;
    gi[node * 768 + 256 + t] = a1[r] + b1v;
    gi[node * 768 + 512 + t] = a2[r] + b2v;
  }
}

// one GRU step: gh = h@Whh^T + bhh, gates, hnew; fused NREG=1 regression accumulation
__global__ __launch_bounds__(256) void k_gru(const float* __restrict__ gi,
                                             const float* __restrict__ whhT,
                                             const float* __restrict__ bhh,
                                             const float* __restrict__ reg_w,
                                             const float* __restrict__ reg_b,
                                             float* __restrict__ h,
                                             float* __restrict__ out,
                                             int s) {
  __shared__ __align__(16) float hl[4 * 256];
  __shared__ float red[16];
  const int t = threadIdx.x;
  const int b0 = blockIdx.x * 4;
  for (int idx = t; idx < 1024; idx += 256) hl[idx] = h[b0 * 256 + idx];
  __syncthreads();
  float ar[4] = {0.f, 0.f, 0.f, 0.f};
  float az[4] = {0.f, 0.f, 0.f, 0.f};
  float an[4] = {0.f, 0.f, 0.f, 0.f};
  for (int c4 = 0; c4 < 64; ++c4) {
    const int c = c4 * 4;
    float wr0 = whhT[c * 768 + t];
    float wr1 = whhT[(c + 1) * 768 + t];
    float wr2 = whhT[(c + 2) * 768 + t];
    float wr3 = whhT[(c + 3) * 768 + t];
    float wz0 = whhT[c * 768 + 256 + t];
    float wz1 = whhT[(c + 1) * 768 + 256 + t];
    float wz2 = whhT[(c + 2) * 768 + 256 + t];
    float wz3 = whhT[(c + 3) * 768 + 256 + t];
    float wn0 = whhT[c * 768 + 512 + t];
    float wn1 = whhT[(c + 1) * 768 + 512 + t];
    float wn2 = whhT[(c + 2) * 768 + 512 + t];
    float wn3 = whhT[(c + 3) * 768 + 512 + t];
#pragma unroll
    for (int r = 0; r < 4; ++r) {
      float4 hv = *(const float4*)&hl[r * 256 + c];
      ar[r] += hv.x * wr0 + hv.y * wr1 + hv.z * wr2 + hv.w * wr3;
      az[r] += hv.x * wz0 + hv.y * wz1 + hv.z * wz2 + hv.w * wz3;
      an[r] += hv.x * wn0 + hv.y * wn1 + hv.z * wn2 + hv.w * wn3;
    }
  }
  float bhr = bhh[t], bhz = bhh[256 + t], bhn = bhh[512 + t];
  float rw = reg_w[s * 256 + t];
  float hnew[4];
#pragma unroll
  for (int r = 0; r < 4; ++r) {
    int node = (b0 + r) * 10 + s;
    float gir = gi[node * 768 + t];
    float giz = gi[node * 768 + 256 + t];
    float gin = gi[node * 768 + 512 + t];
    float ghr = ar[r] + bhr, ghz = az[r] + bhz, ghn = an[r] + bhn;
    float rg = 1.f / (1.f + expf(-(gir + ghr)));
    float zg = 1.f / (1.f + expf(-(giz + ghz)));
    float ng = tanhf(gin + rg * ghn);
    hnew[r] = (1.f - zg) * ng + zg * hl[r * 256 + t];
  }
#pragma unroll
  for (int r = 0; r < 4; ++r) h[(b0 + r) * 256 + t] = hnew[r];
#pragma unroll
  for (int r = 0; r < 4; ++r) {
    float v = hnew[r] * rw;
    v += __shfl_down(v, 32); v += __shfl_down(v, 16); v += __shfl_down(v, 8);
    v += __shfl_down(v, 4);  v += __shfl_down(v, 2);  v += __shfl_down(v, 1);
    if ((t & 63) == 0) red[(t >> 6) * 4 + r] = v;
  }
  __syncthreads();
  if (t < 4) {
    float tot = red[t] + red[4 + t] + red[8 + t] + red[12 + t];
    float prev = (s == 0) ? reg_b[0] : out[b0 + t];
    out[b0 + t] = prev + tot;
  }
}

extern "C" void kernel_launch(void* const* d_in, const int* in_sizes, int n_in,
                              void* d_out, int out_size, void* d_ws, size_t ws_size,
                              hipStream_t stream) {
  (void)in_sizes; (void)n_in; (void)out_size; (void)ws_size;
  const float* lags      = (const float*)d_in[0];
  const float* weather   = (const float*)d_in[1];
  const float* event     = (const float*)d_in[2];
  const int*   text      = (const int*)d_in[3];
  const float* emb       = (const float*)d_in[4];
  const float* conv3_w   = (const float*)d_in[5];
  const float* conv3_b   = (const float*)d_in[6];
  const float* conv4_w   = (const float*)d_in[7];
  const float* conv4_b   = (const float*)d_in[8];
  const float* lags_w    = (const float*)d_in[9];
  const float* lags_b    = (const float*)d_in[10];
  const float* weather_w = (const float*)d_in[11];
  const float* weather_b = (const float*)d_in[12];
  const float* event_w   = (const float*)d_in[13];
  const float* event_b   = (const float*)d_in[14];
  const float* text_w    = (const float*)d_in[15];
  const float* text_b    = (const float*)d_in[16];
  const float* merge_w   = (const float*)d_in[17];
  const float* merge_b   = (const float*)d_in[18];
  const float* bn_gamma  = (const float*)d_in[19];
  const float* bn_beta   = (const float*)d_in[20];
  const float* mh_w      = (const float*)d_in[21];
  const float* mh_b      = (const float*)d_in[22];
  const float* gru_wih   = (const float*)d_in[23];
  const float* gru_whh   = (const float*)d_in[24];
  const float* gru_bih   = (const float*)d_in[25];
  const float* gru_bhh   = (const float*)d_in[26];
  const float* reg_w     = (const float*)d_in[27];
  const float* reg_b     = (const float*)d_in[28];
  float* out = (float*)d_out;

  float* p = (float*)d_ws;
  float* h_buf    = p; p += 262144;     // [1024][256]  (zeroed)
  float* bnsum    = p; p += 256;        // (zeroed)
  float* bnsumsq  = p; p += 256;        // (zeroed)
  float* mx       = p; p += 10240 * 128;
  float* m_buf    = p; p += 10240 * 256;
  float* gi       = p; p += 10240 * 768;
  float* w3p      = p; p += 25600;
  float* w4p      = p; p += 65536;
  float* whhT     = p; p += 196608;
  float* Wcomb    = p; p += 196608;
  float* WbigT    = p; p += 196608;
  float* MtxT     = p; p += 32768;
  float* A_l      = p; p += 256;
  float* MwT      = p; p += 512;
  float* MeT      = p; p += 1024;
  float* bias_deg = p; p += 256;
  float* b1       = p; p += 768;
  float* bias_big = p; p += 768;
  float* svec     = p; p += 256;
  float* tvec     = p; p += 256;

  k_zero<<<dim3(1026), dim3(256), 0, stream>>>(h_buf, 262656);
  k_repack3<<<dim3(100), dim3(256), 0, stream>>>(conv3_w, w3p);
  k_repack4<<<dim3(256), dim3(256), 0, stream>>>(conv4_w, w4p);
  k_whht<<<dim3(768), dim3(256), 0, stream>>>(gru_whh, whhT);
  k_pcomb<<<dim3(768), dim3(256), 0, stream>>>(gru_wih, mh_w, mh_b, gru_bih, Wcomb, b1);
  k_pmerge<<<dim3(129), dim3(256), 0, stream>>>(merge_w, text_w, lags_w, weather_w, event_w,
                                                lags_b, weather_b, event_b, text_b,
                                                MtxT, A_l, MwT, MeT, bias_deg);
  k_textcnn<<<dim3(10240), dim3(256), 0, stream>>>(text, emb, w3p, conv3_b, w4p, conv4_b, mx);
  k_merge<<<dim3(640), dim3(256), 0, stream>>>(mx, lags, weather, event, MtxT, A_l, MwT, MeT,
                                               bias_deg, merge_b, m_buf, bnsum, bnsumsq);
  k_bna<<<dim3(1), dim3(256), 0, stream>>>(bnsum, bnsumsq, bn_gamma, bn_beta, svec, tvec);
  k_bnb<<<dim3(768), dim3(256), 0, stream>>>(Wcomb, svec, WbigT);
  k_bnc<<<dim3(768), dim3(256), 0, stream>>>(Wcomb, tvec, b1, bias_big);
  k_gi<<<dim3(640), dim3(256), 0, stream>>>(m_buf, WbigT, bias_big, gi);
  for (int s = 0; s < 10; ++s)
    k_gru<<<dim3(256), dim3(256), 0, stream>>>(gi, whhT, gru_bhh, reg_w, reg_b, h_buf, out, s);
}

// Round 2
// 761.966 us; speedup vs baseline: 2.4123x; 2.4123x over previous
//
#include <hip/hip_runtime.h>
#include <math.h>

// ---------------------------------------------------------------------------
// Model dims: BS=1024 T=10 N=10240 H=256 C=128 E=50 SEQ=50 V=50000 NREG=1
// R1: textCNN (77% of runtime) moved to bf16 MFMA 16x16x32.
//   conv3: M=48(p) N=128(c) K=192 (tap-major k=kk*64+e, e padded to 64)
//   conv4: M=48(p) N=128(c) K=512 (tap-major k=kk*128+ci)
//   A-frags: 1x ds_read_b128 from XOR-swizzled LDS act tile (no im2col).
//   B-frags: prepacked frag-linear in ws, 1x global_load_dwordx4 (L2).
// ---------------------------------------------------------------------------

typedef unsigned short u16;
typedef __attribute__((ext_vector_type(8))) short short8v;   // 8 bf16 = 4 VGPR
typedef __attribute__((ext_vector_type(4))) float float4v;
#define MFMA16 __builtin_amdgcn_mfma_f32_16x16x32_bf16

__device__ inline u16 f2bf(float f) {
  unsigned u = __float_as_uint(f);
  u += 0x7FFFu + ((u >> 16) & 1u);            // RNE
  return (u16)(u >> 16);
}

__global__ __launch_bounds__(256) void k_zero(float* __restrict__ p, int n) {
  int i = blockIdx.x * 256 + threadIdx.x;
  if (i < n) p[i] = 0.f;
}

// conv3 weights [c=128][e=50][kk=3] -> frag-linear B: [kt=6][nt=8][lane=64][j=8]
// GEMM k = kt*32 + (lane>>4)*8 + j ; kk = k>>6, e = k&63 (e>=50 -> 0)
__global__ __launch_bounds__(256) void k_repb3(const float* __restrict__ w3,
                                               u16* __restrict__ w3b) {
  int i = blockIdx.x * 256 + threadIdx.x;     // 24576
  if (i >= 24576) return;
  int j = i & 7, l = (i >> 3) & 63, nt = (i >> 9) & 7, kt = i >> 12;
  int k = kt * 32 + (l >> 4) * 8 + j;
  int c = nt * 16 + (l & 15);
  int kk = k >> 6, e = k & 63;
  float v = (e < 50) ? w3[c * 150 + e * 3 + kk] : 0.f;
  w3b[i] = f2bf(v);
}

// conv4 weights [c=128][ci=128][kk=4] -> frag-linear B: [kt=16][nt=8][lane][j]
// GEMM k = kt*32 + (lane>>4)*8 + j ; kk = k>>7, ci = k&127
__global__ __launch_bounds__(256) void k_repb4(const float* __restrict__ w4,
                                               u16* __restrict__ w4b) {
  int i = blockIdx.x * 256 + threadIdx.x;     // 65536
  int j = i & 7, l = (i >> 3) & 63, nt = (i >> 9) & 7, kt = i >> 12;
  int k = kt * 32 + (l >> 4) * 8 + j;
  int c = nt * 16 + (l & 15);
  int kk = k >> 7, ci = k & 127;
  w4b[i] = f2bf(w4[c * 512 + ci * 4 + kk]);
}

// gru_whh [768][256] -> whhT [c=256][j=768]
__global__ __launch_bounds__(256) void k_whht(const float* __restrict__ whh,
                                              float* __restrict__ whhT) {
  int j = blockIdx.x, t = threadIdx.x;
  whhT[t * 768 + j] = whh[j * 256 + t];
}

// Wcomb[g][c] = sum_j gru_wih[g][j]*mh_w[j][c];  b1[g] = gru_bih[g] + wih[g]@mh_b
__global__ __launch_bounds__(256) void k_pcomb(const float* __restrict__ wih,
                                               const float* __restrict__ mh_w,
                                               const float* __restrict__ mh_b,
                                               const float* __restrict__ bih,
                                               float* __restrict__ Wcomb,
                                               float* __restrict__ b1) {
  int g = blockIdx.x, t = threadIdx.x;
  float acc = 0.f;
  for (int j = 0; j < 256; ++j) acc += wih[g * 256 + j] * mh_w[j * 256 + t];
  Wcomb[g * 256 + t] = acc;
  float accb = wih[g * 256 + t] * mh_b[t];
  accb += __shfl_down(accb, 32); accb += __shfl_down(accb, 16);
  accb += __shfl_down(accb, 8);  accb += __shfl_down(accb, 4);
  accb += __shfl_down(accb, 2);  accb += __shfl_down(accb, 1);
  __shared__ float red[4];
  if ((t & 63) == 0) red[t >> 6] = accb;
  __syncthreads();
  if (t == 0) b1[g] = bih[g] + red[0] + red[1] + red[2] + red[3];
}

// Fold lags/weather/event/text projections through merge_w.
__global__ __launch_bounds__(256) void k_pmerge(const float* __restrict__ merge_w,
                                                const float* __restrict__ text_w,
                                                const float* __restrict__ lags_w,
                                                const float* __restrict__ weather_w,
                                                const float* __restrict__ event_w,
                                                const float* __restrict__ lags_b,
                                                const float* __restrict__ weather_b,
                                                const float* __restrict__ event_b,
                                                const float* __restrict__ text_b,
                                                float* __restrict__ MtxT,
                                                float* __restrict__ A_l,
                                                float* __restrict__ MwT,
                                                float* __restrict__ MeT,
                                                float* __restrict__ bias_deg) {
  int blk = blockIdx.x, t = threadIdx.x;
  if (blk < 128) {
    int c = blk;
    float acc = 0.f;
    for (int j = 0; j < 256; ++j)
      acc += merge_w[t * 1024 + 768 + j] * text_w[j * 128 + c];
    MtxT[c * 256 + t] = acc;
  } else {
    float a = 0.f, w0 = 0.f, w1 = 0.f, e0 = 0.f, e1 = 0.f, e2 = 0.f, e3 = 0.f, bd = 0.f;
    for (int j = 0; j < 256; ++j) {
      float m0 = merge_w[t * 1024 + j];
      float m1 = merge_w[t * 1024 + 256 + j];
      float m2 = merge_w[t * 1024 + 512 + j];
      float m3 = merge_w[t * 1024 + 768 + j];
      a  += m0 * lags_w[j];
      w0 += m1 * weather_w[j * 2 + 0];
      w1 += m1 * weather_w[j * 2 + 1];
      e0 += m2 * event_w[j * 4 + 0];
      e1 += m2 * event_w[j * 4 + 1];
      e2 += m2 * event_w[j * 4 + 2];
      e3 += m2 * event_w[j * 4 + 3];
      bd += m0 * lags_b[j] + m1 * weather_b[j] + m2 * event_b[j] + m3 * text_b[j];
    }
    A_l[t] = a;
    MwT[t] = w0; MwT[256 + t] = w1;
    MeT[t] = e0; MeT[256 + t] = e1; MeT[512 + t] = e2; MeT[768 + t] = e3;
    bias_deg[t] = bd;
  }
}

// ---------------------------------------------------------------------------
// MFMA textCNN: one wave per node. LDS ~19.7KB -> 8 blocks/CU.
//   sx : [s=50][blk=8][8]   bf16, XOR-swizzled 16B blocks (blk ^= s&7)
//   sc3: [p'=52][blk=16][8] bf16, XOR-swizzled low 3 block bits (^= p&7)
// Fragment conventions (gfx950 mfma_f32_16x16x32_bf16):
//   A lane l elem j: A[l&15][(l>>4)*8+j]; B: B[(l>>4)*8+j][l&15]
//   D lane l reg r : D[(l>>4)*4+r][l&15]   (guide §3, m89-verified)
// ---------------------------------------------------------------------------

#define LOADB(DST, SRC, KT)                                                    \
  _Pragma("unroll") for (int nt = 0; nt < 8; ++nt)                             \
      DST[nt] = *(const short8v*)&SRC[((((KT) * 8 + nt) * 64) + l) * 8];

#define AFRAG3(AF, KT) {                                                       \
    const int kk_ = (KT) >> 1;                                                 \
    const int eb_ = 4 * ((KT) & 1) + g;                                        \
    _Pragma("unroll") for (int mt = 0; mt < 3; ++mt) {                         \
      int pr_ = 16 * mt + lr + kk_;                                            \
      int bb_ = eb_ ^ (pr_ & 7);                                               \
      AF[mt] = *(const short8v*)&sx[pr_ * 64 + bb_ * 8];                       \
    } }

#define AFRAG4(AF, KT) {                                                       \
    const int t4_ = 4 * (KT) + g;                                              \
    const int kk_ = t4_ >> 4;                                                  \
    const int bk_ = t4_ & 15;                                                  \
    _Pragma("unroll") for (int mt = 0; mt < 3; ++mt) {                         \
      int pr_ = 16 * mt + lr + kk_;                                            \
      int bb_ = (bk_ & 8) | ((bk_ ^ pr_) & 7);                                 \
      AF[mt] = *(const short8v*)&sc3[pr_ * 128 + bb_ * 8];                     \
    } }

#define MSTEP(AF, BF)                                                          \
  _Pragma("unroll") for (int nt = 0; nt < 8; ++nt)                             \
    _Pragma("unroll") for (int mt = 0; mt < 3; ++mt)                           \
      acc[mt][nt] = MFMA16(AF[mt], BF[nt], acc[mt][nt], 0, 0, 0);

__global__ __launch_bounds__(64) void k_textcnn(const int* __restrict__ text,
                                                const float* __restrict__ emb,
                                                const u16* __restrict__ w3b,
                                                const float* __restrict__ b3,
                                                const u16* __restrict__ w4b,
                                                const float* __restrict__ b4,
                                                float* __restrict__ mx_g) {
  __shared__ u16 sx[50 * 64];
  __shared__ u16 sc3[52 * 128];
  const int n = blockIdx.x;
  const int l = threadIdx.x;          // 0..63
  const int lr = l & 15;
  const int g = l >> 4;

  // ---- stage emb -> sx (bf16, swizzled); cols e>=50 zeroed ----
  int idxv = (l < 50) ? text[n * 50 + l] : 0;
  const int e = l;
#pragma unroll 10
  for (int s = 0; s < 50; ++s) {
    int id = __shfl(idxv, s);
    float v = (e < 50) ? emb[id * 50 + e] : 0.f;
    int bb = (e >> 3) ^ (s & 7);
    sx[s * 64 + bb * 8 + (e & 7)] = f2bf(v);
  }
  __syncthreads();

  const float4v zv = {0.f, 0.f, 0.f, 0.f};
  float4v acc[3][8];
#pragma unroll
  for (int mt = 0; mt < 3; ++mt)
#pragma unroll
    for (int nt = 0; nt < 8; ++nt) acc[mt][nt] = zv;

  float b3v[8];
#pragma unroll
  for (int nt = 0; nt < 8; ++nt) b3v[nt] = b3[nt * 16 + lr];

  // ---- conv3: 6 k-tiles, B double-buffered in regs ----
  {
    short8v bA[8], bB[8], a[3];
    LOADB(bA, w3b, 0);
    for (int kt = 0; kt < 6; kt += 2) {
      LOADB(bB, w3b, kt + 1);
      AFRAG3(a, kt);
      MSTEP(a, bA);
      if (kt + 2 < 6) LOADB(bA, w3b, kt + 2);
      AFRAG3(a, kt + 1);
      MSTEP(a, bB);
    }
  }

  // ---- bias+relu+cvt -> sc3 (swizzled); re-zero acc ----
#pragma unroll
  for (int mt = 0; mt < 3; ++mt)
#pragma unroll
    for (int nt = 0; nt < 8; ++nt) {
#pragma unroll
      for (int r = 0; r < 4; ++r) {
        int p = 16 * mt + 4 * g + r;
        int c = 16 * nt + lr;
        float v = fmaxf(acc[mt][nt][r] + b3v[nt], 0.f);
        int bb = (c >> 3) & 15;
        bb = (bb & 8) | ((bb ^ (p & 7)) & 7);
        sc3[p * 128 + bb * 8 + (c & 7)] = f2bf(v);
      }
      acc[mt][nt] = zv;
    }
  __syncthreads();

  // ---- conv4: 16 k-tiles ----
  {
    short8v bA[8], bB[8], a[3];
    LOADB(bA, w4b, 0);
    for (int kt = 0; kt < 16; kt += 2) {
      LOADB(bB, w4b, kt + 1);
      AFRAG4(a, kt);
      MSTEP(a, bA);
      if (kt + 2 < 16) LOADB(bA, w4b, kt + 2);
      AFRAG4(a, kt + 1);
      MSTEP(a, bB);
    }
  }

  // ---- max over valid p (<45), +bias, relu, store ----
#pragma unroll
  for (int nt = 0; nt < 8; ++nt) {
    float m0 = -1e30f;
#pragma unroll
    for (int mt = 0; mt < 3; ++mt)
#pragma unroll
      for (int r = 0; r < 4; ++r) {
        int p = 16 * mt + 4 * g + r;
        if (p < 45) m0 = fmaxf(m0, acc[mt][nt][r]);
      }
    m0 = fmaxf(m0, __shfl_xor(m0, 16));
    m0 = fmaxf(m0, __shfl_xor(m0, 32));
    int c = 16 * nt + lr;
    float bias = b4[c];
    if (g == 0) mx_g[n * 128 + c] = fmaxf(m0 + bias, 0.f);
  }
}

__device__ inline void preds_of(int i, int& p1, int& p2, int& d) {
  int tt = i % 10;
  int base = i - tt;
  if (tt == 0)      { p1 = base + 9;      p2 = -1;             d = 1; }
  else if (tt == 1) { p1 = base;          p2 = -1;             d = 1; }
  else              { p1 = base + tt - 2; p2 = base + tt - 1;  d = 2; }
}

// graph agg + folded merge -> m[N][256] (relu'd), + BN channel sums via atomics
__global__ __launch_bounds__(256) void k_merge(const float* __restrict__ mx_g,
                                               const float* __restrict__ lags,
                                               const float* __restrict__ weather,
                                               const float* __restrict__ event,
                                               const float* __restrict__ MtxT,
                                               const float* __restrict__ A_l,
                                               const float* __restrict__ MwT,
                                               const float* __restrict__ MeT,
                                               const float* __restrict__ bias_deg,
                                               const float* __restrict__ merge_b,
                                               float* __restrict__ m_out,
                                               float* __restrict__ bnsum,
                                               float* __restrict__ bnsumsq) {
  __shared__ __align__(16) float mxs[16 * 128];
  __shared__ float scal[16 * 8];
  const int tid = threadIdx.x;
  const int row0 = blockIdx.x * 16;
  for (int idx = tid; idx < 2048; idx += 256) {
    int r = idx >> 7, c = idx & 127;
    int p1, p2, d;
    preds_of(row0 + r, p1, p2, d);
    float v = mx_g[p1 * 128 + c];
    if (p2 >= 0) v += mx_g[p2 * 128 + c];
    mxs[r * 128 + c] = v;
  }
  if (tid < 16) {
    int p1, p2, d;
    preds_of(row0 + tid, p1, p2, d);
    float sl = lags[p1];
    float sw0 = weather[p1 * 2], sw1 = weather[p1 * 2 + 1];
    float se0 = event[p1 * 4], se1 = event[p1 * 4 + 1];
    float se2 = event[p1 * 4 + 2], se3 = event[p1 * 4 + 3];
    if (p2 >= 0) {
      sl += lags[p2];
      sw0 += weather[p2 * 2]; sw1 += weather[p2 * 2 + 1];
      se0 += event[p2 * 4];     se1 += event[p2 * 4 + 1];
      se2 += event[p2 * 4 + 2]; se3 += event[p2 * 4 + 3];
    }
    scal[tid * 8 + 0] = sl;
    scal[tid * 8 + 1] = sw0; scal[tid * 8 + 2] = sw1;
    scal[tid * 8 + 3] = se0; scal[tid * 8 + 4] = se1;
    scal[tid * 8 + 5] = se2; scal[tid * 8 + 6] = se3;
    scal[tid * 8 + 7] = (float)d;
  }
  __syncthreads();
  const int t = tid;
  float acc[16];
#pragma unroll
  for (int r = 0; r < 16; ++r) acc[r] = 0.f;
  for (int c4 = 0; c4 < 32; ++c4) {
    const int c = c4 * 4;
    float w0 = MtxT[c * 256 + t];
    float w1 = MtxT[(c + 1) * 256 + t];
    float w2 = MtxT[(c + 2) * 256 + t];
    float w3 = MtxT[(c + 3) * 256 + t];
#pragma unroll
    for (int r = 0; r < 16; ++r) {
      float4 mv = *(const float4*)&mxs[r * 128 + c];
      acc[r] += mv.x * w0 + mv.y * w1 + mv.z * w2 + mv.w * w3;
    }
  }
  float al = A_l[t], mw0 = MwT[t], mw1 = MwT[256 + t];
  float me0 = MeT[t], me1 = MeT[256 + t], me2 = MeT[512 + t], me3 = MeT[768 + t];
  float bd = bias_deg[t], mb = merge_b[t];
  float s1 = 0.f, s2 = 0.f;
#pragma unroll
  for (int r = 0; r < 16; ++r) {
    float mp = acc[r] + scal[r * 8] * al + scal[r * 8 + 1] * mw0 + scal[r * 8 + 2] * mw1
             + scal[r * 8 + 3] * me0 + scal[r * 8 + 4] * me1 + scal[r * 8 + 5] * me2
             + scal[r * 8 + 6] * me3 + scal[r * 8 + 7] * bd + mb;
    float mv = fmaxf(mp, 0.f);
    m_out[(row0 + r) * 256 + t] = mv;
    s1 += mv;
    s2 += mv * mv;
  }
  atomicAdd(&bnsum[t], s1);
  atomicAdd(&bnsumsq[t], s2);
}

__global__ __launch_bounds__(256) void k_bna(const float* __restrict__ bnsum,
                                             const float* __restrict__ bnsumsq,
                                             const float* __restrict__ gamma,
                                             const float* __restrict__ beta,
                                             float* __restrict__ svec,
                                             float* __restrict__ tvec) {
  int c = threadIdx.x;
  float mu = bnsum[c] * (1.f / 10240.f);
  float var = bnsumsq[c] * (1.f / 10240.f) - mu * mu;
  float s = gamma[c] * rsqrtf(var + 1e-5f);
  svec[c] = s;
  tvec[c] = beta[c] - mu * s;
}

__global__ __launch_bounds__(256) void k_bnb(const float* __restrict__ Wcomb,
                                             const float* __restrict__ svec,
                                             float* __restrict__ WbigT) {
  int i = blockIdx.x * 256 + threadIdx.x;   // 196608
  int c = i / 768, gg = i - c * 768;
  WbigT[i] = Wcomb[gg * 256 + c] * svec[c];
}

__global__ __launch_bounds__(256) void k_bnc(const float* __restrict__ Wcomb,
                                             const float* __restrict__ tvec,
                                             const float* __restrict__ b1,
                                             float* __restrict__ bias_big) {
  int gg = blockIdx.x, c = threadIdx.x;
  float part = tvec[c] * Wcomb[gg * 256 + c];
  part += __shfl_down(part, 32); part += __shfl_down(part, 16);
  part += __shfl_down(part, 8);  part += __shfl_down(part, 4);
  part += __shfl_down(part, 2);  part += __shfl_down(part, 1);
  __shared__ float red[4];
  if ((c & 63) == 0) red[c >> 6] = part;
  __syncthreads();
  if (c == 0) bias_big[gg] = b1[gg] + red[0] + red[1] + red[2] + red[3];
}

// gi[N][768] = m @ WbigT + bias_big   (BN+mh+Wih folded)
__global__ __launch_bounds__(256) void k_gi(const float* __restrict__ m,
                                            const float* __restrict__ WbigT,
                                            const float* __restrict__ bias_big,
                                            float* __restrict__ gi) {
  __shared__ __align__(16) float ml[16 * 256];
  const int t = threadIdx.x;
  const int row0 = blockIdx.x * 16;
  for (int idx = t; idx < 4096; idx += 256) ml[idx] = m[row0 * 256 + idx];
  __syncthreads();
  float a0[16], a1[16], a2[16];
#pragma unroll
  for (int r = 0; r < 16; ++r) { a0[r] = 0.f; a1[r] = 0.f; a2[r] = 0.f; }
  for (int c4 = 0; c4 < 64; ++c4) {
    const int c = c4 * 4;
    float w00 = WbigT[c * 768 + t];
    float w01 = WbigT[(c + 1) * 768 + t];
    float w02 = WbigT[(c + 2) * 768 + t];
    float w03 = WbigT[(c + 3) * 768 + t];
    float w10 = WbigT[c * 768 + 256 + t];
    float w11 = WbigT[(c + 1) * 768 + 256 + t];
    float w12 = WbigT[(c + 2) * 768 + 256 + t];
    float w13 = WbigT[(c + 3) * 768 + 256 + t];
    float w20 = WbigT[c * 768 + 512 + t];
    float w21 = WbigT[(c + 1) * 768 + 512 + t];
    float w22 = WbigT[(c + 2) * 768 + 512 + t];
    float w23 = WbigT[(c + 3) * 768 + 512 + t];
#pragma unroll
    for (int r = 0; r < 16; ++r) {
      float4 mv = *(const float4*)&ml[r * 256 + c];
      a0[r] += mv.x * w00 + mv.y * w01 + mv.z * w02 + mv.w * w03;
      a1[r] += mv.x * w10 + mv.y * w11 + mv.z * w12 + mv.w * w13;
      a2[r] += mv.x * w20 + mv.y * w21 + mv.z * w22 + mv.w * w23;
    }
  }
  float b0 = bias_big[t], b1v = bias_big[256 + t], b2v = bias_big[512 + t];
#pragma unroll
  for (int r = 0; r < 16; ++r) {
    int node = row0 + r;
    gi[node * 768 + t] = a0[r] + b0;
    gi[node * 768 + 256 + t] = a1[r] + b1v;
    gi[node * 768 + 512 + t] = a2[r] + b2v;
  }
}

// one GRU step + fused NREG=1 regression accumulation
__global__ __launch_bounds__(256) void k_gru(const float* __restrict__ gi,
                                             const float* __restrict__ whhT,
                                             const float* __restrict__ bhh,
                                             const float* __restrict__ reg_w,
                                             const float* __restrict__ reg_b,
                                             float* __restrict__ h,
                                             float* __restrict__ out,
                                             int s) {
  __shared__ __align__(16) float hl[4 * 256];
  __shared__ float red[16];
  const int t = threadIdx.x;
  const int b0 = blockIdx.x * 4;
  for (int idx = t; idx < 1024; idx += 256) hl[idx] = h[b0 * 256 + idx];
  __syncthreads();
  float ar[4] = {0.f, 0.f, 0.f, 0.f};
  float az[4] = {0.f, 0.f, 0.f, 0.f};
  float an[4] = {0.f, 0.f, 0.f, 0.f};
  for (int c4 = 0; c4 < 64; ++c4) {
    const int c = c4 * 4;
    float wr0 = whhT[c * 768 + t];
    float wr1 = whhT[(c + 1) * 768 + t];
    float wr2 = whhT[(c + 2) * 768 + t];
    float wr3 = whhT[(c + 3) * 768 + t];
    float wz0 = whhT[c * 768 + 256 + t];
    float wz1 = whhT[(c + 1) * 768 + 256 + t];
    float wz2 = whhT[(c + 2) * 768 + 256 + t];
    float wz3 = whhT[(c + 3) * 768 + 256 + t];
    float wn0 = whhT[c * 768 + 512 + t];
    float wn1 = whhT[(c + 1) * 768 + 512 + t];
    float wn2 = whhT[(c + 2) * 768 + 512 + t];
    float wn3 = whhT[(c + 3) * 768 + 512 + t];
#pragma unroll
    for (int r = 0; r < 4; ++r) {
      float4 hv = *(const float4*)&hl[r * 256 + c];
      ar[r] += hv.x * wr0 + hv.y * wr1 + hv.z * wr2 + hv.w * wr3;
      az[r] += hv.x * wz0 + hv.y * wz1 + hv.z * wz2 + hv.w * wz3;
      an[r] += hv.x * wn0 + hv.y * wn1 + hv.z * wn2 + hv.w * wn3;
    }
  }
  float bhr = bhh[t], bhz = bhh[256 + t], bhn = bhh[512 + t];
  float rw = reg_w[s * 256 + t];
  float hnew[4];
#pragma unroll
  for (int r = 0; r < 4; ++r) {
    int node = (b0 + r) * 10 + s;
    float gir = gi[node * 768 + t];
    float giz = gi[node * 768 + 256 + t];
    float gin = gi[node * 768 + 512 + t];
    float ghr = ar[r] + bhr, ghz = az[r] + bhz, ghn = an[r] + bhn;
    float rg = 1.f / (1.f + expf(-(gir + ghr)));
    float zg = 1.f / (1.f + expf(-(giz + ghz)));
    float ng = tanhf(gin + rg * ghn);
    hnew[r] = (1.f - zg) * ng + zg * hl[r * 256 + t];
  }
#pragma unroll
  for (int r = 0; r < 4; ++r) h[(b0 + r) * 256 + t] = hnew[r];
#pragma unroll
  for (int r = 0; r < 4; ++r) {
    float v = hnew[r] * rw;
    v += __shfl_down(v, 32); v += __shfl_down(v, 16); v += __shfl_down(v, 8);
    v += __shfl_down(v, 4);  v += __shfl_down(v, 2);  v += __shfl_down(v, 1);
    if ((t & 63) == 0) red[(t >> 6) * 4 + r] = v;
  }
  __syncthreads();
  if (t < 4) {
    float tot = red[t] + red[4 + t] + red[8 + t] + red[12 + t];
    float prev = (s == 0) ? reg_b[0] : out[b0 + t];
    out[b0 + t] = prev + tot;
  }
}

extern "C" void kernel_launch(void* const* d_in, const int* in_sizes, int n_in,
                              void* d_out, int out_size, void* d_ws, size_t ws_size,
                              hipStream_t stream) {
  (void)in_sizes; (void)n_in; (void)out_size; (void)ws_size;
  const float* lags      = (const float*)d_in[0];
  const float* weather   = (const float*)d_in[1];
  const float* event     = (const float*)d_in[2];
  const int*   text      = (const int*)d_in[3];
  const float* emb       = (const float*)d_in[4];
  const float* conv3_w   = (const float*)d_in[5];
  const float* conv3_b   = (const float*)d_in[6];
  const float* conv4_w   = (const float*)d_in[7];
  const float* conv4_b   = (const float*)d_in[8];
  const float* lags_w    = (const float*)d_in[9];
  const float* lags_b    = (const float*)d_in[10];
  const float* weather_w = (const float*)d_in[11];
  const float* weather_b = (const float*)d_in[12];
  const float* event_w   = (const float*)d_in[13];
  const float* event_b   = (const float*)d_in[14];
  const float* text_w    = (const float*)d_in[15];
  const float* text_b    = (const float*)d_in[16];
  const float* merge_w   = (const float*)d_in[17];
  const float* merge_b   = (const float*)d_in[18];
  const float* bn_gamma  = (const float*)d_in[19];
  const float* bn_beta   = (const float*)d_in[20];
  const float* mh_w      = (const float*)d_in[21];
  const float* mh_b      = (const float*)d_in[22];
  const float* gru_wih   = (const float*)d_in[23];
  const float* gru_whh   = (const float*)d_in[24];
  const float* gru_bih   = (const float*)d_in[25];
  const float* gru_bhh   = (const float*)d_in[26];
  const float* reg_w     = (const float*)d_in[27];
  const float* reg_b     = (const float*)d_in[28];
  float* out = (float*)d_out;

  float* p = (float*)d_ws;
  float* h_buf    = p; p += 262144;     // [1024][256]  (zeroed)
  float* bnsum    = p; p += 256;        // (zeroed)
  float* bnsumsq  = p; p += 256;        // (zeroed)
  float* mx       = p; p += 10240 * 128;
  float* m_buf    = p; p += 10240 * 256;
  float* gi       = p; p += 10240 * 768;
  u16*   w3b      = (u16*)p; p += 12288;    // 24576 u16
  u16*   w4b      = (u16*)p; p += 32768;    // 65536 u16
  float* whhT     = p; p += 196608;
  float* Wcomb    = p; p += 196608;
  float* WbigT    = p; p += 196608;
  float* MtxT     = p; p += 32768;
  float* A_l      = p; p += 256;
  float* MwT      = p; p += 512;
  float* MeT      = p; p += 1024;
  float* bias_deg = p; p += 256;
  float* b1       = p; p += 768;
  float* bias_big = p; p += 768;
  float* svec     = p; p += 256;
  float* tvec     = p; p += 256;

  k_zero<<<dim3(1026), dim3(256), 0, stream>>>(h_buf, 262656);
  k_repb3<<<dim3(96), dim3(256), 0, stream>>>(conv3_w, w3b);
  k_repb4<<<dim3(256), dim3(256), 0, stream>>>(conv4_w, w4b);
  k_whht<<<dim3(768), dim3(256), 0, stream>>>(gru_whh, whhT);
  k_pcomb<<<dim3(768), dim3(256), 0, stream>>>(gru_wih, mh_w, mh_b, gru_bih, Wcomb, b1);
  k_pmerge<<<dim3(129), dim3(256), 0, stream>>>(merge_w, text_w, lags_w, weather_w, event_w,
                                                lags_b, weather_b, event_b, text_b,
                                                MtxT, A_l, MwT, MeT, bias_deg);
  k_textcnn<<<dim3(10240), dim3(64), 0, stream>>>(text, emb, w3b, conv3_b, w4b, conv4_b, mx);
  k_merge<<<dim3(640), dim3(256), 0, stream>>>(mx, lags, weather, event, MtxT, A_l, MwT, MeT,
                                               bias_deg, merge_b, m_buf, bnsum, bnsumsq);
  k_bna<<<dim3(1), dim3(256), 0, stream>>>(bnsum, bnsumsq, bn_gamma, bn_beta, svec, tvec);
  k_bnb<<<dim3(768), dim3(256), 0, stream>>>(Wcomb, svec, WbigT);
  k_bnc<<<dim3(768), dim3(256), 0, stream>>>(Wcomb, tvec, b1, bias_big);
  k_gi<<<dim3(640), dim3(256), 0, stream>>>(m_buf, WbigT, bias_big, gi);
  for (int s = 0; s < 10; ++s)
    k_gru<<<dim3(256), dim3(256), 0, stream>>>(gi, whhT, gru_bhh, reg_w, reg_b, h_buf, out, s);
}

// Round 4
// 667.320 us; speedup vs baseline: 2.7545x; 1.1418x over previous
//
#include <hip/hip_runtime.h>
#include <math.h>

// ---------------------------------------------------------------------------
// Model dims: BS=1024 T=10 H=256 C=128 E=50 SEQ=50 V=50000 NREG=1
// R2 (resubmit; R3 bench never ran — GPU acquisition timeout):
//     (a) textcnn LDS alias sx/sc3 -> 13.3KB/wave -> 12 waves/CU
//     (b) GRU fused to ONE kernel, bf16 MFMA, gate-interleaved N-tiles
//     (c) k_gi bf16 MFMA (m stored bf16 by k_merge)
//     (d) 13 launches total
// ---------------------------------------------------------------------------

typedef unsigned short u16;
typedef __attribute__((ext_vector_type(8))) short short8v;   // 8 bf16 = 4 VGPR
typedef __attribute__((ext_vector_type(4))) float float4v;
#define MFMA16 __builtin_amdgcn_mfma_f32_16x16x32_bf16

__device__ inline u16 f2bf(float f) {
  unsigned u = __float_as_uint(f);
  u += 0x7FFFu + ((u >> 16) & 1u);            // RNE
  return (u16)(u >> 16);
}

__global__ __launch_bounds__(256) void k_zero(float* __restrict__ p, int n) {
  int i = blockIdx.x * 256 + threadIdx.x;
  if (i < n) p[i] = 0.f;
}

// conv3 weights [c=128][e=50][kk=3] -> frag-linear B: [kt=6][nt=8][lane=64][j=8]
__global__ __launch_bounds__(256) void k_repb3(const float* __restrict__ w3,
                                               u16* __restrict__ w3b) {
  int i = blockIdx.x * 256 + threadIdx.x;     // 24576
  if (i >= 24576) return;
  int j = i & 7, l = (i >> 3) & 63, nt = (i >> 9) & 7, kt = i >> 12;
  int k = kt * 32 + (l >> 4) * 8 + j;
  int c = nt * 16 + (l & 15);
  int kk = k >> 6, e = k & 63;
  float v = (e < 50) ? w3[c * 150 + e * 3 + kk] : 0.f;
  w3b[i] = f2bf(v);
}

// conv4 weights [c=128][ci=128][kk=4] -> frag-linear B: [kt=16][nt=8][lane][j]
__global__ __launch_bounds__(256) void k_repb4(const float* __restrict__ w4,
                                               u16* __restrict__ w4b) {
  int i = blockIdx.x * 256 + threadIdx.x;     // 65536
  int j = i & 7, l = (i >> 3) & 63, nt = (i >> 9) & 7, kt = i >> 12;
  int k = kt * 32 + (l >> 4) * 8 + j;
  int c = nt * 16 + (l & 15);
  int kk = k >> 7, ci = k & 127;
  w4b[i] = f2bf(w4[c * 512 + ci * 4 + kk]);
}

// gru_whh [768][256] -> bf16 frag-linear B for gh GEMM: B[k][n]=whh[n][k]
// idx = ((nt*8+kt)*64 + l)*8 + j ; n = nt*16+(l&15), k = kt*32+(l>>4)*8+j
__global__ __launch_bounds__(256) void k_repwhh(const float* __restrict__ whh,
                                                u16* __restrict__ whhb) {
  int i = blockIdx.x * 256 + threadIdx.x;     // 196608
  int j = i & 7, l = (i >> 3) & 63, kt = (i >> 9) & 7, nt = i >> 12;
  int n = nt * 16 + (l & 15);
  int k = kt * 32 + (l >> 4) * 8 + j;
  whhb[i] = f2bf(whh[n * 256 + k]);
}

// Wcomb[g][c] = gru_wih[g]@mh_w[:,c]; b1[g] = gru_bih[g] + wih[g]@mh_b
// 8 g-rows per block (amortize mh_w traffic 201MB -> 25MB)
__global__ __launch_bounds__(256) void k_pcomb(const float* __restrict__ wih,
                                               const float* __restrict__ mh_w,
                                               const float* __restrict__ mh_b,
                                               const float* __restrict__ bih,
                                               float* __restrict__ Wcomb,
                                               float* __restrict__ b1) {
  int g0 = blockIdx.x * 8, t = threadIdx.x;
  float acc[8] = {0.f, 0.f, 0.f, 0.f, 0.f, 0.f, 0.f, 0.f};
  for (int j = 0; j < 256; ++j) {
    float wv = mh_w[j * 256 + t];
#pragma unroll
    for (int r = 0; r < 8; ++r) acc[r] += wih[(g0 + r) * 256 + j] * wv;
  }
#pragma unroll
  for (int r = 0; r < 8; ++r) Wcomb[(g0 + r) * 256 + t] = acc[r];
  __shared__ float red[4][8];
  float mb = mh_b[t];
#pragma unroll
  for (int r = 0; r < 8; ++r) {
    float v = wih[(g0 + r) * 256 + t] * mb;
    v += __shfl_down(v, 32); v += __shfl_down(v, 16); v += __shfl_down(v, 8);
    v += __shfl_down(v, 4);  v += __shfl_down(v, 2);  v += __shfl_down(v, 1);
    if ((t & 63) == 0) red[t >> 6][r] = v;
  }
  __syncthreads();
  if (t < 8) b1[g0 + t] = bih[g0 + t] + red[0][t] + red[1][t] + red[2][t] + red[3][t];
}

// Fold lags/weather/event/text projections through merge_w.
__global__ __launch_bounds__(256) void k_pmerge(const float* __restrict__ merge_w,
                                                const float* __restrict__ text_w,
                                                const float* __restrict__ lags_w,
                                                const float* __restrict__ weather_w,
                                                const float* __restrict__ event_w,
                                                const float* __restrict__ lags_b,
                                                const float* __restrict__ weather_b,
                                                const float* __restrict__ event_b,
                                                const float* __restrict__ text_b,
                                                float* __restrict__ MtxT,
                                                float* __restrict__ A_l,
                                                float* __restrict__ MwT,
                                                float* __restrict__ MeT,
                                                float* __restrict__ bias_deg) {
  int blk = blockIdx.x, t = threadIdx.x;
  if (blk < 128) {
    int c = blk;
    float acc = 0.f;
    for (int j = 0; j < 256; ++j)
      acc += merge_w[t * 1024 + 768 + j] * text_w[j * 128 + c];
    MtxT[c * 256 + t] = acc;
  } else {
    float a = 0.f, w0 = 0.f, w1 = 0.f, e0 = 0.f, e1 = 0.f, e2 = 0.f, e3 = 0.f, bd = 0.f;
    for (int j = 0; j < 256; ++j) {
      float m0 = merge_w[t * 1024 + j];
      float m1 = merge_w[t * 1024 + 256 + j];
      float m2 = merge_w[t * 1024 + 512 + j];
      float m3 = merge_w[t * 1024 + 768 + j];
      a  += m0 * lags_w[j];
      w0 += m1 * weather_w[j * 2 + 0];
      w1 += m1 * weather_w[j * 2 + 1];
      e0 += m2 * event_w[j * 4 + 0];
      e1 += m2 * event_w[j * 4 + 1];
      e2 += m2 * event_w[j * 4 + 2];
      e3 += m2 * event_w[j * 4 + 3];
      bd += m0 * lags_b[j] + m1 * weather_b[j] + m2 * event_b[j] + m3 * text_b[j];
    }
    A_l[t] = a;
    MwT[t] = w0; MwT[256 + t] = w1;
    MeT[t] = e0; MeT[256 + t] = e1; MeT[512 + t] = e2; MeT[768 + t] = e3;
    bias_deg[t] = bd;
  }
}

// ---------------------------------------------------------------------------
// MFMA textCNN. LDS: sx (6.4KB) aliased with sc3 (13.3KB) -> 13.3KB/wave
// -> 12 blocks/CU (was 8). Barrier between last sx read and first sc3 write.
// ---------------------------------------------------------------------------

#define LOADB(DST, SRC, KT)                                                    \
  _Pragma("unroll") for (int nt = 0; nt < 8; ++nt)                             \
      DST[nt] = *(const short8v*)&SRC[((((KT) * 8 + nt) * 64) + l) * 8];

#define AFRAG3(AF, KT) {                                                       \
    const int kk_ = (KT) >> 1;                                                 \
    const int eb_ = 4 * ((KT) & 1) + g;                                        \
    _Pragma("unroll") for (int mt = 0; mt < 3; ++mt) {                         \
      int pr_ = 16 * mt + lr + kk_;                                            \
      int bb_ = eb_ ^ (pr_ & 7);                                               \
      AF[mt] = *(const short8v*)&sx[pr_ * 64 + bb_ * 8];                       \
    } }

#define AFRAG4(AF, KT) {                                                       \
    const int t4_ = 4 * (KT) + g;                                              \
    const int kk_ = t4_ >> 4;                                                  \
    const int bk_ = t4_ & 15;                                                  \
    _Pragma("unroll") for (int mt = 0; mt < 3; ++mt) {                         \
      int pr_ = 16 * mt + lr + kk_;                                            \
      int bb_ = (bk_ & 8) | ((bk_ ^ pr_) & 7);                                 \
      AF[mt] = *(const short8v*)&sc3[pr_ * 128 + bb_ * 8];                     \
    } }

#define MSTEP(AF, BF)                                                          \
  _Pragma("unroll") for (int nt = 0; nt < 8; ++nt)                             \
    _Pragma("unroll") for (int mt = 0; mt < 3; ++mt)                           \
      acc[mt][nt] = MFMA16(AF[mt], BF[nt], acc[mt][nt], 0, 0, 0);

__global__ __launch_bounds__(64) void k_textcnn(const int* __restrict__ text,
                                                const float* __restrict__ emb,
                                                const u16* __restrict__ w3b,
                                                const float* __restrict__ b3,
                                                const u16* __restrict__ w4b,
                                                const float* __restrict__ b4,
                                                float* __restrict__ mx_g) {
  __shared__ u16 sbuf[52 * 128];      // union: sx (3200 u16) | sc3 (6656 u16)
  u16* sx = sbuf;
  u16* sc3 = sbuf;
  const int n = blockIdx.x;
  const int l = threadIdx.x;          // 0..63
  const int lr = l & 15;
  const int g = l >> 4;

  // ---- stage emb -> sx (bf16, swizzled); cols e>=50 zeroed ----
  int idxv = (l < 50) ? text[n * 50 + l] : 0;
  const int e = l;
#pragma unroll 10
  for (int s = 0; s < 50; ++s) {
    int id = __shfl(idxv, s);
    float v = (e < 50) ? emb[id * 50 + e] : 0.f;
    int bb = (e >> 3) ^ (s & 7);
    sx[s * 64 + bb * 8 + (e & 7)] = f2bf(v);
  }
  __syncthreads();

  const float4v zv = {0.f, 0.f, 0.f, 0.f};
  float4v acc[3][8];
#pragma unroll
  for (int mt = 0; mt < 3; ++mt)
#pragma unroll
    for (int nt = 0; nt < 8; ++nt) acc[mt][nt] = zv;

  float b3v[8];
#pragma unroll
  for (int nt = 0; nt < 8; ++nt) b3v[nt] = b3[nt * 16 + lr];

  // ---- conv3: 6 k-tiles, B double-buffered in regs ----
  {
    short8v bA[8], bB[8], a[3];
    LOADB(bA, w3b, 0);
    for (int kt = 0; kt < 6; kt += 2) {
      LOADB(bB, w3b, kt + 1);
      AFRAG3(a, kt);
      MSTEP(a, bA);
      if (kt + 2 < 6) LOADB(bA, w3b, kt + 2);
      AFRAG3(a, kt + 1);
      MSTEP(a, bB);
    }
  }
  __syncthreads();   // sx reads done before sc3 overwrites (aliased)

  // ---- bias+relu+cvt -> sc3 (swizzled); re-zero acc ----
#pragma unroll
  for (int mt = 0; mt < 3; ++mt)
#pragma unroll
    for (int nt = 0; nt < 8; ++nt) {
#pragma unroll
      for (int r = 0; r < 4; ++r) {
        int p = 16 * mt + 4 * g + r;
        int c = 16 * nt + lr;
        float v = fmaxf(acc[mt][nt][r] + b3v[nt], 0.f);
        int bb = (c >> 3) & 15;
        bb = (bb & 8) | ((bb ^ (p & 7)) & 7);
        sc3[p * 128 + bb * 8 + (c & 7)] = f2bf(v);
      }
      acc[mt][nt] = zv;
    }
  __syncthreads();

  // ---- conv4: 16 k-tiles ----
  {
    short8v bA[8], bB[8], a[3];
    LOADB(bA, w4b, 0);
    for (int kt = 0; kt < 16; kt += 2) {
      LOADB(bB, w4b, kt + 1);
      AFRAG4(a, kt);
      MSTEP(a, bA);
      if (kt + 2 < 16) LOADB(bA, w4b, kt + 2);
      AFRAG4(a, kt + 1);
      MSTEP(a, bB);
    }
  }

  // ---- max over valid p (<45), +bias, relu, store ----
#pragma unroll
  for (int nt = 0; nt < 8; ++nt) {
    float m0 = -1e30f;
#pragma unroll
    for (int mt = 0; mt < 3; ++mt)
#pragma unroll
      for (int r = 0; r < 4; ++r) {
        int p = 16 * mt + 4 * g + r;
        if (p < 45) m0 = fmaxf(m0, acc[mt][nt][r]);
      }
    m0 = fmaxf(m0, __shfl_xor(m0, 16));
    m0 = fmaxf(m0, __shfl_xor(m0, 32));
    int c = 16 * nt + lr;
    float bias = b4[c];
    if (g == 0) mx_g[n * 128 + c] = fmaxf(m0 + bias, 0.f);
  }
}

__device__ inline void preds_of(int i, int& p1, int& p2, int& d) {
  int tt = i % 10;
  int base = i - tt;
  if (tt == 0)      { p1 = base + 9;      p2 = -1;             d = 1; }
  else if (tt == 1) { p1 = base;          p2 = -1;             d = 1; }
  else              { p1 = base + tt - 2; p2 = base + tt - 1;  d = 2; }
}

// graph agg + folded merge -> m_bf[N][256] (bf16, pre-BN, relu'd) + BN sums
__global__ __launch_bounds__(256) void k_merge(const float* __restrict__ mx_g,
                                               const float* __restrict__ lags,
                                               const float* __restrict__ weather,
                                               const float* __restrict__ event,
                                               const float* __restrict__ MtxT,
                                               const float* __restrict__ A_l,
                                               const float* __restrict__ MwT,
                                               const float* __restrict__ MeT,
                                               const float* __restrict__ bias_deg,
                                               const float* __restrict__ merge_b,
                                               u16* __restrict__ m_bf,
                                               float* __restrict__ bnsum,
                                               float* __restrict__ bnsumsq) {
  __shared__ __align__(16) float mxs[16 * 128];
  __shared__ float scal[16 * 8];
  const int tid = threadIdx.x;
  const int row0 = blockIdx.x * 16;
  for (int idx = tid; idx < 2048; idx += 256) {
    int r = idx >> 7, c = idx & 127;
    int p1, p2, d;
    preds_of(row0 + r, p1, p2, d);
    float v = mx_g[p1 * 128 + c];
    if (p2 >= 0) v += mx_g[p2 * 128 + c];
    mxs[r * 128 + c] = v;
  }
  if (tid < 16) {
    int p1, p2, d;
    preds_of(row0 + tid, p1, p2, d);
    float sl = lags[p1];
    float sw0 = weather[p1 * 2], sw1 = weather[p1 * 2 + 1];
    float se0 = event[p1 * 4], se1 = event[p1 * 4 + 1];
    float se2 = event[p1 * 4 + 2], se3 = event[p1 * 4 + 3];
    if (p2 >= 0) {
      sl += lags[p2];
      sw0 += weather[p2 * 2]; sw1 += weather[p2 * 2 + 1];
      se0 += event[p2 * 4];     se1 += event[p2 * 4 + 1];
      se2 += event[p2 * 4 + 2]; se3 += event[p2 * 4 + 3];
    }
    scal[tid * 8 + 0] = sl;
    scal[tid * 8 + 1] = sw0; scal[tid * 8 + 2] = sw1;
    scal[tid * 8 + 3] = se0; scal[tid * 8 + 4] = se1;
    scal[tid * 8 + 5] = se2; scal[tid * 8 + 6] = se3;
    scal[tid * 8 + 7] = (float)d;
  }
  __syncthreads();
  const int t = tid;
  float acc[16];
#pragma unroll
  for (int r = 0; r < 16; ++r) acc[r] = 0.f;
  for (int c4 = 0; c4 < 32; ++c4) {
    const int c = c4 * 4;
    float w0 = MtxT[c * 256 + t];
    float w1 = MtxT[(c + 1) * 256 + t];
    float w2 = MtxT[(c + 2) * 256 + t];
    float w3 = MtxT[(c + 3) * 256 + t];
#pragma unroll
    for (int r = 0; r < 16; ++r) {
      float4 mv = *(const float4*)&mxs[r * 128 + c];
      acc[r] += mv.x * w0 + mv.y * w1 + mv.z * w2 + mv.w * w3;
    }
  }
  float al = A_l[t], mw0 = MwT[t], mw1 = MwT[256 + t];
  float me0 = MeT[t], me1 = MeT[256 + t], me2 = MeT[512 + t], me3 = MeT[768 + t];
  float bd = bias_deg[t], mb = merge_b[t];
  float s1 = 0.f, s2 = 0.f;
#pragma unroll
  for (int r = 0; r < 16; ++r) {
    float mp = acc[r] + scal[r * 8] * al + scal[r * 8 + 1] * mw0 + scal[r * 8 + 2] * mw1
             + scal[r * 8 + 3] * me0 + scal[r * 8 + 4] * me1 + scal[r * 8 + 5] * me2
             + scal[r * 8 + 6] * me3 + scal[r * 8 + 7] * bd + mb;
    float mv = fmaxf(mp, 0.f);
    m_bf[(row0 + r) * 256 + t] = f2bf(mv);
    s1 += mv;
    s2 += mv * mv;
  }
  atomicAdd(&bnsum[t], s1);
  atomicAdd(&bnsumsq[t], s2);
}

__global__ __launch_bounds__(256) void k_bna(const float* __restrict__ bnsum,
                                             const float* __restrict__ bnsumsq,
                                             const float* __restrict__ gamma,
                                             const float* __restrict__ beta,
                                             float* __restrict__ svec,
                                             float* __restrict__ tvec) {
  int c = threadIdx.x;
  float mu = bnsum[c] * (1.f / 10240.f);
  float var = bnsumsq[c] * (1.f / 10240.f) - mu * mu;
  float s = gamma[c] * rsqrtf(var + 1e-5f);
  svec[c] = s;
  tvec[c] = beta[c] - mu * s;
}

// blocks 0..767: wbig_b (bf16 frag-linear, BN scale folded)
// blocks 768..1535: bias_big[g] = b1[g] + tvec@Wcomb[g]
__global__ __launch_bounds__(256) void k_bnbc(const float* __restrict__ Wcomb,
                                              const float* __restrict__ svec,
                                              const float* __restrict__ tvec,
                                              const float* __restrict__ b1,
                                              u16* __restrict__ wbig_b,
                                              float* __restrict__ bias_big) {
  int blk = blockIdx.x, t = threadIdx.x;
  __shared__ float red[4];
  if (blk < 768) {
    int i = blk * 256 + t;
    int j = i & 7, l = (i >> 3) & 63, kt = (i >> 9) & 7, nt = i >> 12;
    int n = nt * 16 + (l & 15);
    int k = kt * 32 + (l >> 4) * 8 + j;
    wbig_b[i] = f2bf(Wcomb[n * 256 + k] * svec[k]);
  } else {
    int gg = blk - 768;
    float part = tvec[t] * Wcomb[gg * 256 + t];
    part += __shfl_down(part, 32); part += __shfl_down(part, 16);
    part += __shfl_down(part, 8);  part += __shfl_down(part, 4);
    part += __shfl_down(part, 2);  part += __shfl_down(part, 1);
    if ((t & 63) == 0) red[t >> 6] = part;
    __syncthreads();
    if (t == 0) bias_big[gg] = b1[gg] + red[0] + red[1] + red[2] + red[3];
  }
}

// gi[N][768] = m @ Wbig^T + bias_big  (bf16 MFMA; BN+mh+Wih folded)
// 640 blocks x 16 rows; wave w owns nt in [w*12, w*12+12)
__global__ __launch_bounds__(256) void k_gi(const u16* __restrict__ m_bf,
                                            const u16* __restrict__ wbig_b,
                                            const float* __restrict__ bias_big,
                                            float* __restrict__ gi) {
  const int t = threadIdx.x;
  const int w = t >> 6, l = t & 63, lr = l & 15, g = l >> 4;
  const int row0 = blockIdx.x * 16;
  short8v a[8];
#pragma unroll
  for (int kt = 0; kt < 8; ++kt)
    a[kt] = *(const short8v*)&m_bf[(row0 + lr) * 256 + kt * 32 + g * 8];
  const float4v zv = {0.f, 0.f, 0.f, 0.f};
  float4v acc[12];
#pragma unroll
  for (int j = 0; j < 12; ++j) acc[j] = zv;
#pragma unroll 2
  for (int kt = 0; kt < 8; ++kt) {
#pragma unroll
    for (int j = 0; j < 12; ++j) {
      int nt = w * 12 + j;
      short8v b = *(const short8v*)&wbig_b[((nt * 8 + kt) * 64 + l) * 8];
      acc[j] = MFMA16(a[kt], b, acc[j], 0, 0, 0);
    }
  }
#pragma unroll
  for (int j = 0; j < 12; ++j) {
    int col = (w * 12 + j) * 16 + lr;
    float bb = bias_big[col];
#pragma unroll
    for (int r = 0; r < 4; ++r)
      gi[(row0 + g * 4 + r) * 768 + col] = acc[j][r] + bb;
  }
}

// ---------------------------------------------------------------------------
// Fused GRU, all 10 steps in one kernel. 64 blocks x 16 rows x 4 waves.
// gh = h@whh^T via MFMA; gate-interleaved nt = gate*16 + w*4 + i so each lane
// holds its (r,z,n) triple in-register. h: bf16 in swizzled LDS (A-operand)
// + f32 in per-lane regs (hp). reg-dot accumulated across steps in regs.
// ---------------------------------------------------------------------------
__global__ __launch_bounds__(256) void k_gru_all(const float* __restrict__ gi,
                                                 const u16* __restrict__ whhb,
                                                 const float* __restrict__ bhh,
                                                 const float* __restrict__ reg_w,
                                                 const float* __restrict__ reg_b,
                                                 float* __restrict__ out) {
  __shared__ u16 hb[16 * 256];
  __shared__ float red[4][16];
  const int t = threadIdx.x;
  const int w = t >> 6, l = t & 63, lr = l & 15, g = l >> 4;
  const int row0 = blockIdx.x * 16;
  for (int i = t; i < 4096; i += 256) hb[i] = 0;
  float hp[4][4];                    // [i][r] : h for (row g*4+r, col (w*4+i)*16+lr)
#pragma unroll
  for (int i = 0; i < 4; ++i)
#pragma unroll
    for (int r = 0; r < 4; ++r) hp[i][r] = 0.f;
  float bh[3][4];
#pragma unroll
  for (int gate = 0; gate < 3; ++gate)
#pragma unroll
    for (int i = 0; i < 4; ++i)
      bh[gate][i] = bhh[gate * 256 + (w * 4 + i) * 16 + lr];
  float racc[4] = {0.f, 0.f, 0.f, 0.f};

  for (int s = 0; s < 10; ++s) {
    __syncthreads();                 // hb (init or prev-step writes) visible
    const float4v zv = {0.f, 0.f, 0.f, 0.f};
    float4v acc[3][4];
#pragma unroll
    for (int gate = 0; gate < 3; ++gate)
#pragma unroll
      for (int i = 0; i < 4; ++i) acc[gate][i] = zv;
#pragma unroll
    for (int kt = 0; kt < 8; ++kt) {
      int kb = kt * 4 + g;
      int bb = kb ^ (lr & 7);
      short8v a = *(const short8v*)&hb[lr * 256 + bb * 8];
#pragma unroll
      for (int gate = 0; gate < 3; ++gate)
#pragma unroll
        for (int i = 0; i < 4; ++i) {
          int nt = gate * 16 + w * 4 + i;
          short8v b = *(const short8v*)&whhb[((nt * 8 + kt) * 64 + l) * 8];
          acc[gate][i] = MFMA16(a, b, acc[gate][i], 0, 0, 0);
        }
    }
    __syncthreads();                 // all hb reads done before overwrite
    float rw[4];
#pragma unroll
    for (int i = 0; i < 4; ++i) rw[i] = reg_w[s * 256 + (w * 4 + i) * 16 + lr];
#pragma unroll
    for (int i = 0; i < 4; ++i) {
      int c = (w * 4 + i) * 16 + lr;
#pragma unroll
      for (int r = 0; r < 4; ++r) {
        int node = (row0 + g * 4 + r) * 10 + s;
        float gir = gi[node * 768 + c];
        float giz = gi[node * 768 + 256 + c];
        float gin = gi[node * 768 + 512 + c];
        float ghr = acc[0][i][r] + bh[0][i];
        float ghz = acc[1][i][r] + bh[1][i];
        float ghn = acc[2][i][r] + bh[2][i];
        float rg = 1.f / (1.f + expf(-(gir + ghr)));
        float zg = 1.f / (1.f + expf(-(giz + ghz)));
        float ng = tanhf(gin + rg * ghn);
        float hn = (1.f - zg) * ng + zg * hp[i][r];
        hp[i][r] = hn;
        racc[r] += hn * rw[i];
        int m = g * 4 + r;
        int bb2 = (c >> 3) ^ (m & 7);
        hb[m * 256 + bb2 * 8 + (c & 7)] = f2bf(hn);
      }
    }
  }
#pragma unroll
  for (int r = 0; r < 4; ++r) {
    float v = racc[r];
    v += __shfl_xor(v, 1); v += __shfl_xor(v, 2);
    v += __shfl_xor(v, 4); v += __shfl_xor(v, 8);
    racc[r] = v;
  }
  if (lr == 0) {
#pragma unroll
    for (int r = 0; r < 4; ++r) red[w][g * 4 + r] = racc[r];
  }
  __syncthreads();
  if (t < 16)
    out[row0 + t] = reg_b[0] + red[0][t] + red[1][t] + red[2][t] + red[3][t];
}

extern "C" void kernel_launch(void* const* d_in, const int* in_sizes, int n_in,
                              void* d_out, int out_size, void* d_ws, size_t ws_size,
                              hipStream_t stream) {
  (void)in_sizes; (void)n_in; (void)out_size; (void)ws_size;
  const float* lags      = (const float*)d_in[0];
  const float* weather   = (const float*)d_in[1];
  const float* event     = (const float*)d_in[2];
  const int*   text      = (const int*)d_in[3];
  const float* emb       = (const float*)d_in[4];
  const float* conv3_w   = (const float*)d_in[5];
  const float* conv3_b   = (const float*)d_in[6];
  const float* conv4_w   = (const float*)d_in[7];
  const float* conv4_b   = (const float*)d_in[8];
  const float* lags_w    = (const float*)d_in[9];
  const float* lags_b    = (const float*)d_in[10];
  const float* weather_w = (const float*)d_in[11];
  const float* weather_b = (const float*)d_in[12];
  const float* event_w   = (const float*)d_in[13];
  const float* event_b   = (const float*)d_in[14];
  const float* text_w    = (const float*)d_in[15];
  const float* text_b    = (const float*)d_in[16];
  const float* merge_w   = (const float*)d_in[17];
  const float* merge_b   = (const float*)d_in[18];
  const float* bn_gamma  = (const float*)d_in[19];
  const float* bn_beta   = (const float*)d_in[20];
  const float* mh_w      = (const float*)d_in[21];
  const float* mh_b      = (const float*)d_in[22];
  const float* gru_wih   = (const float*)d_in[23];
  const float* gru_whh   = (const float*)d_in[24];
  const float* gru_bih   = (const float*)d_in[25];
  const float* gru_bhh   = (const float*)d_in[26];
  const float* reg_w     = (const float*)d_in[27];
  const float* reg_b     = (const float*)d_in[28];
  float* out = (float*)d_out;

  float* p = (float*)d_ws;
  float* bnsum    = p; p += 256;            // zeroed
  float* bnsumsq  = p; p += 256;            // zeroed
  float* mx       = p; p += 10240 * 128;
  u16*   m_bf     = (u16*)p; p += 10240 * 128;   // 10240*256 u16
  float* gi       = p; p += 10240 * 768;
  u16*   w3b      = (u16*)p; p += 12288;    // 24576 u16
  u16*   w4b      = (u16*)p; p += 32768;    // 65536 u16
  u16*   whhb     = (u16*)p; p += 98304;    // 196608 u16
  u16*   wbig_b   = (u16*)p; p += 98304;    // 196608 u16
  float* Wcomb    = p; p += 196608;
  float* MtxT     = p; p += 32768;
  float* A_l      = p; p += 256;
  float* MwT      = p; p += 512;
  float* MeT      = p; p += 1024;
  float* bias_deg = p; p += 256;
  float* b1       = p; p += 768;
  float* bias_big = p; p += 768;
  float* svec     = p; p += 256;
  float* tvec     = p; p += 256;

  k_zero<<<dim3(2), dim3(256), 0, stream>>>(bnsum, 512);
  k_repb3<<<dim3(96), dim3(256), 0, stream>>>(conv3_w, w3b);
  k_repb4<<<dim3(256), dim3(256), 0, stream>>>(conv4_w, w4b);
  k_repwhh<<<dim3(768), dim3(256), 0, stream>>>(gru_whh, whhb);
  k_pcomb<<<dim3(96), dim3(256), 0, stream>>>(gru_wih, mh_w, mh_b, gru_bih, Wcomb, b1);
  k_pmerge<<<dim3(129), dim3(256), 0, stream>>>(merge_w, text_w, lags_w, weather_w, event_w,
                                                lags_b, weather_b, event_b, text_b,
                                                MtxT, A_l, MwT, MeT, bias_deg);
  k_textcnn<<<dim3(10240), dim3(64), 0, stream>>>(text, emb, w3b, conv3_b, w4b, conv4_b, mx);
  k_merge<<<dim3(640), dim3(256), 0, stream>>>(mx, lags, weather, event, MtxT, A_l, MwT, MeT,
                                               bias_deg, merge_b, m_bf, bnsum, bnsumsq);
  k_bna<<<dim3(1), dim3(256), 0, stream>>>(bnsum, bnsumsq, bn_gamma, bn_beta, svec, tvec);
  k_bnbc<<<dim3(1536), dim3(256), 0, stream>>>(Wcomb, svec, tvec, b1, wbig_b, bias_big);
  k_gi<<<dim3(640), dim3(256), 0, stream>>>(m_bf, wbig_b, bias_big, gi);
  k_gru_all<<<dim3(64), dim3(256), 0, stream>>>(gi, whhb, gru_bhh, reg_w, reg_b, out);
}